// Round 14
// baseline (41.903 us; speedup 1.0000x reference)
//
#include <hip/hip_runtime.h>
#include <hip/hip_bf16.h>

typedef float f32x4 __attribute__((ext_vector_type(4)));
typedef short bf16x8 __attribute__((ext_vector_type(8)));

__device__ inline unsigned cvt_pk_bf16(float a, float b) {
    unsigned r;
    asm("v_cvt_pk_bf16_f32 %0, %1, %2" : "=v"(r) : "v"(a), "v"(b));
    return r;
}
union FragU { unsigned u[4]; bf16x8 v; };

__device__ inline bf16x8 pack8(const float* f) {
    FragU x;
    x.u[0] = cvt_pk_bf16(f[0], f[1]);
    x.u[1] = cvt_pk_bf16(f[2], f[3]);
    x.u[2] = cvt_pk_bf16(f[4], f[5]);
    x.u[3] = cvt_pk_bf16(f[6], f[7]);
    return x.v;
}
__device__ inline bf16x8 splat8(float v) {
    FragU x;
    unsigned p = cvt_pk_bf16(v, v);
    x.u[0] = p; x.u[1] = p; x.u[2] = p; x.u[3] = p;
    return x.v;
}
// wave-local LDS ordering (validated R13): drain DS + compiler mem/sched fence
__device__ inline void wave_fence() {
    asm volatile("s_waitcnt lgkmcnt(0)" ::: "memory");
    __builtin_amdgcn_sched_barrier(0);
}

#define POWERS(p, xx)                                              \
    p[0] = 1.f;  p[1] = (xx);      p[2] = p[1]*p[1];               \
    p[3] = p[2]*p[1]; p[4] = p[2]*p[2]; p[5] = p[4]*p[1];          \
    p[6] = p[4]*p[2]; p[7] = p[4]*p[3];

#define TS 72   // [s'][sample] stride: 72 => 2-way-max bank pattern, read2-able pairs

__global__ __launch_bounds__(256) void tt_poly_kernel(
    const float* __restrict__ X,
    const float* __restrict__ G0,   // [d1][r]
    const float* __restrict__ G1,   // [r][d1][s]
    const float* __restrict__ G2,   // [s][d1][t]
    const float* __restrict__ G3,   // [t][d1]
    float* __restrict__ out,
    int B, int NW)
{
    __shared__ float Xb[4][256];        // [sample][4] x-vector per wave
    __shared__ float T1s[4][8 * TS];    // [s'][sample], rows pair-interleaved s'=2*(s&3)+(s>>2)
    __shared__ float T2s[4][8 * TS];

    const int tid  = threadIdx.x;
    const int w    = tid >> 6;
    const int lane = tid & 63;
    const int col  = lane & 15;
    const int grp  = lane >> 4;
    const int gw   = blockIdx.x * 4 + w;

    // ---- prefetch all 4 iterations' X rows (hide HBM under precompute) ----
    float4 xva[4];
    #pragma unroll
    for (int it = 0; it < 4; ++it) {
        int b = (it * NW + gw) * 64 + lane;
        xva[it] = (b < B) ? reinterpret_cast<const float4*>(X)[b]
                          : make_float4(0.f, 0.f, 0.f, 0.f);
    }

    // ---- C-layout calibration + fast-path check (2 probe MFMAs, exact) ----
    int rowLbl[4], colLbl[4], rpL[4];
    bool okl = true;
    {
        bf16x8 ones = splat8(1.f);
        bf16x8 lbl  = splat8((float)col);
        f32x4 pr = {0.f, 0.f, 0.f, 0.f};
        f32x4 pc = {0.f, 0.f, 0.f, 0.f};
        pr = __builtin_amdgcn_mfma_f32_16x16x32_bf16(lbl, ones, pr, 0, 0, 0);
        pc = __builtin_amdgcn_mfma_f32_16x16x32_bf16(ones, lbl, pc, 0, 0, 0);
        #pragma unroll
        for (int j = 0; j < 4; ++j) {
            rowLbl[j] = (int)(pr[j] * 0.03125f + 0.5f);
            colLbl[j] = (int)(pc[j] * 0.03125f + 0.5f);
            rpL[j]    = 2 * (colLbl[j] & 3) + ((colLbl[j] >> 2) & 1);
            okl = okl && (rowLbl[j] == 4 * grp + j) && (colLbl[j] == col);
        }
    }
    const bool vecok = (__ballot(okl) == ~0ull);

    // ---- H1 = G0 (.) G1 fused coefficients, exact fp32 -> bf16 hi+lo split ----
    // H1[e][d][s] = sum_r G0[e][r] * G1[r][d][s]; B-slot (q,grp,j) = H1[4q+grp][j][col]
    bf16x8 H1h[2], H1l[2], B2h[2], B2l[2];
    #pragma unroll
    for (int q = 0; q < 2; ++q) {
        float hi[8], lo[8];
        #pragma unroll
        for (int j = 0; j < 8; ++j) {
            float v = 0.f;
            if (col < 8) {
                #pragma unroll
                for (int r = 0; r < 8; ++r)
                    v = fmaf(G0[(4*q+grp)*8 + r], G1[(r*8 + j)*8 + col], v);
            }
            float h = __bfloat162float(__float2bfloat16(v));
            hi[j] = h; lo[j] = v - h;
        }
        H1h[q] = pack8(hi); H1l[q] = pack8(lo);
    }
    #pragma unroll
    for (int q = 0; q < 2; ++q) {
        float hi[8], lo[8];
        #pragma unroll
        for (int j = 0; j < 8; ++j) {
            float v = (col < 8) ? G2[((4*q+grp)*8 + j)*8 + col] : 0.f;
            float h = __bfloat162float(__float2bfloat16(v));
            hi[j] = h; lo[j] = v - h;
        }
        B2h[q] = pack8(hi); B2l[q] = pack8(lo);
    }

    float* Xw  = &Xb[w][0];
    float* T1w = &T1s[w][0];
    float* T2w = &T2s[w][0];

    #pragma unroll
    for (int it = 0; it < 4; ++it) {
        const int b = (it * NW + gw) * 64 + lane;
        const float4 xv = xva[it];

        // stash own sample's x-vector
        *reinterpret_cast<f32x4*>(&Xw[lane * 4]) = (f32x4){xv.x, xv.y, xv.z, xv.w};
        wave_fence();

        float x2keep[4];

        // ---- S12 (fused): t1 = (P0 (x) P1) @ H1 ----
        #pragma unroll
        for (int g4 = 0; g4 < 4; ++g4) {
            f32x4 xq = *reinterpret_cast<const f32x4*>(&Xw[(g4*16 + col) * 4]);
            x2keep[g4] = xq.z;
            float p1[8];
            POWERS(p1, xq.y)
            float x0 = xq.x;
            float x02 = x0 * x0, x04 = x02 * x02;
            float e1 = (grp & 1) ? x0  : 1.f;
            float e2 = (grp & 2) ? x02 : 1.f;
            float xg = e1 * e2, xg4 = xg * x04;
            float f0[8], f1[8];
            #pragma unroll
            for (int e = 0; e < 8; ++e) { f0[e] = xg * p1[e]; f1[e] = xg4 * p1[e]; }
            bf16x8 a0 = pack8(f0), a1 = pack8(f1);
            f32x4 acc = {0.f, 0.f, 0.f, 0.f};
            acc = __builtin_amdgcn_mfma_f32_16x16x32_bf16(a0, H1h[0], acc, 0, 0, 0);
            acc = __builtin_amdgcn_mfma_f32_16x16x32_bf16(a0, H1l[0], acc, 0, 0, 0);
            acc = __builtin_amdgcn_mfma_f32_16x16x32_bf16(a1, H1h[1], acc, 0, 0, 0);
            acc = __builtin_amdgcn_mfma_f32_16x16x32_bf16(a1, H1l[1], acc, 0, 0, 0);
            if (vecok) {
                if (col < 8) {
                    int rp = 2 * (col & 3) + (col >> 2);
                    *reinterpret_cast<f32x4*>(&T1w[rp * TS + g4*16 + 4*grp]) = acc;
                }
            } else {
                #pragma unroll
                for (int j = 0; j < 4; ++j)
                    if (colLbl[j] < 8)
                        T1w[rpL[j] * TS + g4*16 + rowLbl[j]] = acc[j];
            }
        }
        wave_fence();

        // ---- S3: t2 = (t1 (x) P2) @ G2 ----
        #pragma unroll
        for (int g4 = 0; g4 < 4; ++g4) {
            float t1a = T1w[(2*grp) * TS      + g4*16 + col];   // s = grp
            float t1b = T1w[(2*grp) * TS + TS + g4*16 + col];   // s = grp+4
            float p2[8];
            POWERS(p2, x2keep[g4])
            float f0[8], f1[8];
            #pragma unroll
            for (int e = 0; e < 8; ++e) { f0[e] = t1a * p2[e]; f1[e] = t1b * p2[e]; }
            bf16x8 a0 = pack8(f0), a1 = pack8(f1);
            f32x4 acc = {0.f, 0.f, 0.f, 0.f};
            acc = __builtin_amdgcn_mfma_f32_16x16x32_bf16(a0, B2h[0], acc, 0, 0, 0);
            acc = __builtin_amdgcn_mfma_f32_16x16x32_bf16(a0, B2l[0], acc, 0, 0, 0);
            acc = __builtin_amdgcn_mfma_f32_16x16x32_bf16(a1, B2h[1], acc, 0, 0, 0);
            acc = __builtin_amdgcn_mfma_f32_16x16x32_bf16(a1, B2l[1], acc, 0, 0, 0);
            if (vecok) {
                if (col < 8) {
                    int rp = 2 * (col & 3) + (col >> 2);
                    *reinterpret_cast<f32x4*>(&T2w[rp * TS + g4*16 + 4*grp]) = acc;
                }
            } else {
                #pragma unroll
                for (int j = 0; j < 4; ++j)
                    if (colLbl[j] < 8)
                        T2w[rpL[j] * TS + g4*16 + rowLbl[j]] = acc[j];
            }
        }
        wave_fence();

        // ---- S4: res = sum_t t2[t] * (G3[t] . P3) ----
        {
            float u[8];
            #pragma unroll
            for (int sl = 0; sl < 8; ++sl)
                u[sl] = T2w[sl * TS + lane];
            float p3[8];
            POWERS(p3, xv.w)
            float res = 0.f;
            #pragma unroll
            for (int sl = 0; sl < 8; ++sl) {
                const int t8 = (sl & 1) * 4 + (sl >> 1);   // inverse of rp
                float wt = G3[t8 * 8];
                #pragma unroll
                for (int d = 1; d < 8; ++d)
                    wt = fmaf(p3[d], G3[t8 * 8 + d], wt);
                res = fmaf(u[sl], wt, res);
            }
            if (b < B) out[b] = res;
        }
    }
}

extern "C" void kernel_launch(void* const* d_in, const int* in_sizes, int n_in,
                              void* d_out, int out_size, void* d_ws, size_t ws_size,
                              hipStream_t stream) {
    const float* X  = (const float*)d_in[0];
    const float* G0 = (const float*)d_in[1];
    const float* G1 = (const float*)d_in[2];
    const float* G2 = (const float*)d_in[3];
    const float* G3 = (const float*)d_in[4];
    float* out = (float*)d_out;

    int B = in_sizes[0] / 4;                       // X is [B,4]
    int block = 256;
    int grid = (B + 1023) / 1024;                  // 1024 samples per block
    int NW = grid * 4;
    tt_poly_kernel<<<grid, block, 0, stream>>>(X, G0, G1, G2, G3, out, B, NW);
}

// Round 15
// 40.890 us; speedup vs baseline: 1.0248x; 1.0248x over previous
//
#include <hip/hip_runtime.h>
#include <hip/hip_bf16.h>

typedef float f32x4 __attribute__((ext_vector_type(4)));
typedef short bf16x8 __attribute__((ext_vector_type(8)));

__device__ inline unsigned cvt_pk_bf16(float a, float b) {
    unsigned r;
    asm("v_cvt_pk_bf16_f32 %0, %1, %2" : "=v"(r) : "v"(a), "v"(b));
    return r;
}
union FragU { unsigned u[4]; bf16x8 v; };

__device__ inline bf16x8 pack8(const float* f) {
    FragU x;
    x.u[0] = cvt_pk_bf16(f[0], f[1]);
    x.u[1] = cvt_pk_bf16(f[2], f[3]);
    x.u[2] = cvt_pk_bf16(f[4], f[5]);
    x.u[3] = cvt_pk_bf16(f[6], f[7]);
    return x.v;
}

// exact fp32 -> bf16 hi+lo split of 8 values
__device__ inline void split_hl(const float* v, bf16x8& h8, bf16x8& l8) {
    float hi[8], lo[8];
    #pragma unroll
    for (int e = 0; e < 8; ++e) {
        float h = __bfloat162float(__float2bfloat16(v[e]));
        hi[e] = h; lo[e] = v[e] - h;
    }
    h8 = pack8(hi); l8 = pack8(lo);
}

// cross-lane register moves (no LDS buffer, no fences needed: dep-tracked builtins)
__device__ inline float bperm_f(int idx_bytes, float v) {
    return __int_as_float(__builtin_amdgcn_ds_bpermute(idx_bytes, __float_as_int(v)));
}
__device__ inline float swz16_f(float v) {   // lane ^= 16 within each 32-lane half
    return __int_as_float(__builtin_amdgcn_ds_swizzle(__float_as_int(v), 0x401F));
}

#define POWERS(p, xx)                                              \
    p[0] = 1.f;  p[1] = (xx);      p[2] = p[1]*p[1];               \
    p[3] = p[2]*p[1]; p[4] = p[2]*p[2]; p[5] = p[4]*p[1];          \
    p[6] = p[4]*p[2]; p[7] = p[4]*p[3];

#define MFMA __builtin_amdgcn_mfma_f32_16x16x32_bf16

__global__ __launch_bounds__(256, 2) void tt_poly_kernel(
    const float* __restrict__ X,
    const float* __restrict__ G0,   // [d1][r]
    const float* __restrict__ G1,   // [r][d1][s]
    const float* __restrict__ G2,   // [s][d1][t]
    const float* __restrict__ G3,   // [t][d1]
    float* __restrict__ out,
    int B, int NW)
{
    const int tid   = threadIdx.x;
    const int lane  = tid & 63;
    const int row16 = lane & 15;    // C column: sample-within-group; also A row
    const int quad  = lane >> 4;
    const int s8    = row16 & 7;    // output index this lane's A-row produces (mirrored)
    const int gw    = blockIdx.x * 4 + (tid >> 6);

    // ---- prefetch all 4 iterations' X rows ----
    float4 xva[4];
    #pragma unroll
    for (int it = 0; it < 4; ++it) {
        int b = (it * NW + gw) * 64 + lane;
        xva[it] = (b < B) ? reinterpret_cast<const float4*>(X)[b]
                          : make_float4(0.f, 0.f, 0.f, 0.f);
    }

    // ---- per-wave constant A-fragments (G on A side; rows mirrored via s8) ----
    // S2: A1_q[row][k=8*quad+e] = H1[e][d1=4q+quad][s8],  H1 = G0 . G1 (exact fp32)
    bf16x8 A1h[2], A1l[2], A2h[2], A2l[2], A3h[2], A3l[2];
    #pragma unroll
    for (int q = 0; q < 2; ++q) {
        float v[8];
        #pragma unroll
        for (int e = 0; e < 8; ++e) {
            float a = 0.f;
            #pragma unroll
            for (int r = 0; r < 8; ++r)
                a = fmaf(G0[e*8 + r], G1[(r*8 + 4*q + quad)*8 + s8], a);
            v[e] = a;
        }
        split_hl(v, A1h[q], A1l[q]);
    }
    // S3: A2_q slot e = G2[s=e][d2=4q+quad][t=s8]
    #pragma unroll
    for (int q = 0; q < 2; ++q) {
        float v[8];
        #pragma unroll
        for (int e = 0; e < 8; ++e)
            v[e] = G2[(e*8 + 4*q + quad)*8 + s8];
        split_hl(v, A2h[q], A2l[q]);
    }
    // S4: A3_q slot e = G3[t=e][d3=4q+quad]  (row-independent -> all C rows = res)
    #pragma unroll
    for (int q = 0; q < 2; ++q) {
        float v[8];
        #pragma unroll
        for (int e = 0; e < 8; ++e)
            v[e] = G3[e*8 + 4*q + quad];
        split_hl(v, A3h[q], A3l[q]);
    }

    const bool oddq  = (quad & 1) != 0;
    const float zero = 0.f;

    #pragma unroll
    for (int it = 0; it < 4; ++it) {
        const int sbase = (it * NW + gw) * 64;
        const float4 xv = xva[it];
        float res = 0.f;

        #pragma unroll
        for (int g4 = 0; g4 < 4; ++g4) {
            // broadcast sample (g4*16+row16)'s x to this lane
            const int src = (g4 * 16 + row16) * 4;
            float x0 = bperm_f(src, xv.x);
            float x1 = bperm_f(src, xv.y);
            float x2 = bperm_f(src, xv.z);
            float x3 = bperm_f(src, xv.w);

            // ---- S2: B_q slot e = x0^e * x1^(4q+quad) ----
            float p0[8];
            POWERS(p0, x0)
            float x1sq = x1 * x1, x1q4 = x1sq * x1sq;
            float sA = ((quad & 1) ? x1 : 1.f) * ((quad & 2) ? x1sq : 1.f);
            float sB = sA * x1q4;
            float f0[8], f1[8];
            #pragma unroll
            for (int e = 0; e < 8; ++e) { f0[e] = p0[e] * sA; f1[e] = p0[e] * sB; }
            bf16x8 b0 = pack8(f0), b1 = pack8(f1);
            f32x4 acc = {zero, zero, zero, zero};
            acc = MFMA(A1h[0], b0, acc, 0, 0, 0);
            acc = MFMA(A1l[0], b0, acc, 0, 0, 0);
            acc = MFMA(A1h[1], b1, acc, 0, 0, 0);
            acc = MFMA(A1l[1], b1, acc, 0, 0, 0);

            // gather t1[0..7][row16]: own quad has parity half, partner the other
            float t1v[8];
            {
                float sw0 = swz16_f(acc[0]), sw1 = swz16_f(acc[1]);
                float sw2 = swz16_f(acc[2]), sw3 = swz16_f(acc[3]);
                t1v[0] = oddq ? sw0 : acc[0];  t1v[4] = oddq ? acc[0] : sw0;
                t1v[1] = oddq ? sw1 : acc[1];  t1v[5] = oddq ? acc[1] : sw1;
                t1v[2] = oddq ? sw2 : acc[2];  t1v[6] = oddq ? acc[2] : sw2;
                t1v[3] = oddq ? sw3 : acc[3];  t1v[7] = oddq ? acc[3] : sw3;
            }

            // ---- S3: B_q slot e = t1[e] * x2^(4q+quad) ----
            float x2sq = x2 * x2, x2q4 = x2sq * x2sq;
            float uA = ((quad & 1) ? x2 : 1.f) * ((quad & 2) ? x2sq : 1.f);
            float uB = uA * x2q4;
            #pragma unroll
            for (int e = 0; e < 8; ++e) { f0[e] = t1v[e] * uA; f1[e] = t1v[e] * uB; }
            b0 = pack8(f0); b1 = pack8(f1);
            f32x4 acc2 = {zero, zero, zero, zero};
            acc2 = MFMA(A2h[0], b0, acc2, 0, 0, 0);
            acc2 = MFMA(A2l[0], b0, acc2, 0, 0, 0);
            acc2 = MFMA(A2h[1], b1, acc2, 0, 0, 0);
            acc2 = MFMA(A2l[1], b1, acc2, 0, 0, 0);

            // gather t2[0..7][row16]
            float t2v[8];
            {
                float sw0 = swz16_f(acc2[0]), sw1 = swz16_f(acc2[1]);
                float sw2 = swz16_f(acc2[2]), sw3 = swz16_f(acc2[3]);
                t2v[0] = oddq ? sw0 : acc2[0];  t2v[4] = oddq ? acc2[0] : sw0;
                t2v[1] = oddq ? sw1 : acc2[1];  t2v[5] = oddq ? acc2[1] : sw1;
                t2v[2] = oddq ? sw2 : acc2[2];  t2v[6] = oddq ? acc2[2] : sw2;
                t2v[3] = oddq ? sw3 : acc2[3];  t2v[7] = oddq ? acc2[3] : sw3;
            }

            // ---- S4: B_q slot e = t2[e] * x3^(4q+quad); all C rows = res ----
            float x3sq = x3 * x3, x3q4 = x3sq * x3sq;
            float wA = ((quad & 1) ? x3 : 1.f) * ((quad & 2) ? x3sq : 1.f);
            float wB = wA * x3q4;
            #pragma unroll
            for (int e = 0; e < 8; ++e) { f0[e] = t2v[e] * wA; f1[e] = t2v[e] * wB; }
            b0 = pack8(f0); b1 = pack8(f1);
            f32x4 acc3 = {zero, zero, zero, zero};
            acc3 = MFMA(A3h[0], b0, acc3, 0, 0, 0);
            acc3 = MFMA(A3l[0], b0, acc3, 0, 0, 0);
            acc3 = MFMA(A3h[1], b1, acc3, 0, 0, 0);
            acc3 = MFMA(A3l[1], b1, acc3, 0, 0, 0);

            // keep the chain whose sample block matches this lane's quad
            res = (quad == g4) ? acc3[0] : res;
        }

        const int b = sbase + lane;   // sample == lane (quad*16 + row16)
        if (b < B) out[b] = res;
    }
}

extern "C" void kernel_launch(void* const* d_in, const int* in_sizes, int n_in,
                              void* d_out, int out_size, void* d_ws, size_t ws_size,
                              hipStream_t stream) {
    const float* X  = (const float*)d_in[0];
    const float* G0 = (const float*)d_in[1];
    const float* G1 = (const float*)d_in[2];
    const float* G2 = (const float*)d_in[3];
    const float* G3 = (const float*)d_in[4];
    float* out = (float*)d_out;

    int B = in_sizes[0] / 4;                       // X is [B,4]
    int block = 256;
    int grid = (B + 1023) / 1024;                  // 1024 samples per block
    int NW = grid * 4;                             // total waves
    tt_poly_kernel<<<grid, block, 0, stream>>>(X, G0, G1, G2, G3, out, B, NW);
}